// Round 1
// baseline (829.343 us; speedup 1.0000x reference)
//
#include <hip/hip_runtime.h>

#define N_NODES 50000
#define N_EDGES 1600000
#define F_IN 1433
#define HID 128
#define NCLS 7

// ---- workspace layout (bytes), all 256-aligned ----
#define O_DEG_SRC 0u          // N ints   (200000)
#define O_DEG_DST 200704u     // N ints
#define O_CURSOR  401408u     // N ints
#define O_ROWPTR  602112u     // N+1 ints
#define O_NSRC    802816u     // N floats
#define O_NDST    1003520u    // N floats
#define O_BSUM    1204224u    // 256 ints
#define O_BOFF    1205248u    // 256 ints
#define O_CSR     1206272u    // E ints (6400000)
#define O_H       7606272u    // N*128 floats (25600000), 16B aligned
#define O_H2      33206272u   // N*7 floats (1400000)

__global__ void deg_kernel(const int* __restrict__ src, const int* __restrict__ dst,
                           int* __restrict__ deg_src, int* __restrict__ deg_dst) {
    int e = blockIdx.x * blockDim.x + threadIdx.x;
    if (e < N_EDGES) {
        atomicAdd(&deg_src[src[e]], 1);
        atomicAdd(&deg_dst[dst[e]], 1);
    }
}

__global__ void norm_kernel(const int* __restrict__ deg_src, const int* __restrict__ deg_dst,
                            float* __restrict__ nsrc, float* __restrict__ ndst) {
    int i = blockIdx.x * blockDim.x + threadIdx.x;
    if (i < N_NODES) {
        nsrc[i] = rsqrtf(fmaxf((float)deg_src[i], 1.0f));
        ndst[i] = rsqrtf(fmaxf((float)deg_dst[i], 1.0f));
    }
}

// per-block inclusive scan of deg -> incl, block totals -> bsum
__global__ void scan1_kernel(const int* __restrict__ deg, int* __restrict__ incl,
                             int* __restrict__ bsum) {
    __shared__ int s[256];
    int t = threadIdx.x;
    int i = blockIdx.x * 256 + t;
    int v = (i < N_NODES) ? deg[i] : 0;
    s[t] = v;
    __syncthreads();
    for (int off = 1; off < 256; off <<= 1) {
        int a = (t >= off) ? s[t - off] : 0;
        __syncthreads();
        s[t] += a;
        __syncthreads();
    }
    if (i < N_NODES) incl[i] = s[t];
    if (t == 255) bsum[blockIdx.x] = s[255];
}

// exclusive scan of nb block sums (nb <= 256) -> boff
__global__ void scan2_kernel(const int* __restrict__ bsum, int* __restrict__ boff, int nb) {
    __shared__ int s[256];
    int t = threadIdx.x;
    int v = (t < nb) ? bsum[t] : 0;
    s[t] = v;
    __syncthreads();
    for (int off = 1; off < 256; off <<= 1) {
        int a = (t >= off) ? s[t - off] : 0;
        __syncthreads();
        s[t] += a;
        __syncthreads();
    }
    if (t < nb) boff[t] = s[t] - v;  // exclusive
}

// rowptr[i] (exclusive) = incl[i] - deg[i] + boff[block]
__global__ void scan3_kernel(int* __restrict__ rowptr, const int* __restrict__ deg,
                             const int* __restrict__ boff) {
    int i = blockIdx.x * 256 + threadIdx.x;
    if (i < N_NODES) rowptr[i] = rowptr[i] - deg[i] + boff[blockIdx.x];
}

__global__ void fill_kernel(const int* __restrict__ src, const int* __restrict__ dst,
                            const int* __restrict__ rowptr, int* __restrict__ cursor,
                            int* __restrict__ csr) {
    int e = blockIdx.x * blockDim.x + threadIdx.x;
    if (e < N_EDGES) {
        int d = dst[e];
        int pos = rowptr[d] + atomicAdd(&cursor[d], 1);
        csr[pos] = src[e];
    }
}

// h = (X * nsrc[:,None]) @ W1    [N, 128], f32 tiled
#define BM 64
#define BK 16
__global__ __launch_bounds__(256) void gemm1_kernel(const float* __restrict__ X,
                                                    const float* __restrict__ W1,
                                                    const float* __restrict__ nsrc,
                                                    float* __restrict__ h) {
    __shared__ float As[BK][68];    // [k][m], padded stride 68 (272B: 16B-aligned rows, low bank conflict)
    __shared__ float Bs[BK][HID];   // [k][n]
    int tid = threadIdx.x;
    int bm = blockIdx.x * BM;
    int tx = tid & 15;       // 16 col-groups of 8
    int ty = tid >> 4;       // 16 row-groups of 4
    float acc[4][8];
#pragma unroll
    for (int i = 0; i < 4; i++)
#pragma unroll
        for (int j = 0; j < 8; j++) acc[i][j] = 0.f;

    int a_k = tid & 15;      // k within tile
    int a_m = tid >> 4;      // base row, +16*i
    int b_k = tid >> 5;      // 0..7 (and +8)
    int b_c = (tid & 31) * 4;

    for (int k0 = 0; k0 < F_IN; k0 += BK) {
        // A tile (scaled by nsrc), zero-pad tail
#pragma unroll
        for (int i = 0; i < 4; i++) {
            int m = a_m + 16 * i;
            int row = bm + m;
            float v = 0.f;
            if (row < N_NODES && (k0 + a_k) < F_IN)
                v = X[(long)row * F_IN + k0 + a_k] * nsrc[row];
            As[a_k][m] = v;
        }
        // B tile (float4 rows of W1)
#pragma unroll
        for (int i = 0; i < 2; i++) {
            int kk = b_k + 8 * i;
            float4 v = make_float4(0.f, 0.f, 0.f, 0.f);
            if (k0 + kk < F_IN)
                v = *(const float4*)&W1[(long)(k0 + kk) * HID + b_c];
            *(float4*)&Bs[kk][b_c] = v;
        }
        __syncthreads();
#pragma unroll
        for (int k = 0; k < BK; k++) {
            float4 a = *(const float4*)&As[k][ty * 4];
            float4 b0 = *(const float4*)&Bs[k][tx * 8];
            float4 b1 = *(const float4*)&Bs[k][tx * 8 + 4];
            float av[4] = {a.x, a.y, a.z, a.w};
            float bv[8] = {b0.x, b0.y, b0.z, b0.w, b1.x, b1.y, b1.z, b1.w};
#pragma unroll
            for (int i = 0; i < 4; i++)
#pragma unroll
                for (int j = 0; j < 8; j++) acc[i][j] = fmaf(av[i], bv[j], acc[i][j]);
        }
        __syncthreads();
    }
#pragma unroll
    for (int i = 0; i < 4; i++) {
        int row = bm + ty * 4 + i;
        if (row < N_NODES) {
            float4 o0 = make_float4(acc[i][0], acc[i][1], acc[i][2], acc[i][3]);
            float4 o1 = make_float4(acc[i][4], acc[i][5], acc[i][6], acc[i][7]);
            *(float4*)&h[(long)row * HID + tx * 8] = o0;
            *(float4*)&h[(long)row * HID + tx * 8 + 4] = o1;
        }
    }
}

// per dst node: agg = sum h[src], x1' = relu(agg*nd + b1)*ns, h2 = x1' @ W2
__global__ __launch_bounds__(256) void agg1_kernel(const float* __restrict__ h,
                                                   const int* __restrict__ csr,
                                                   const int* __restrict__ rowptr,
                                                   const int* __restrict__ deg,
                                                   const float* __restrict__ ndst,
                                                   const float* __restrict__ nsrc,
                                                   const float* __restrict__ b1,
                                                   const float* __restrict__ W2,
                                                   float* __restrict__ h2) {
    int wid = threadIdx.x >> 6, lane = threadIdx.x & 63;
    int node = blockIdx.x * 4 + wid;
    if (node >= N_NODES) return;
    int rp = rowptr[node], dg = deg[node];
    float acc0 = 0.f, acc1 = 0.f;
    for (int p = rp; p < rp + dg; ++p) {
        int s = csr[p];
        float2 hv = *(const float2*)(h + (long)s * HID + 2 * lane);
        acc0 += hv.x;
        acc1 += hv.y;
    }
    float nd = ndst[node], ns = nsrc[node];
    int k0 = 2 * lane;
    float x0 = fmaxf(acc0 * nd + b1[k0], 0.f) * ns;
    float x1 = fmaxf(acc1 * nd + b1[k0 + 1], 0.f) * ns;
#pragma unroll
    for (int c = 0; c < NCLS; c++) {
        float p = x0 * W2[k0 * NCLS + c] + x1 * W2[(k0 + 1) * NCLS + c];
#pragma unroll
        for (int off = 1; off < 64; off <<= 1) p += __shfl_xor(p, off);
        if (lane == c) h2[(long)node * NCLS + c] = p;
    }
}

// per dst node: out = (sum h2[src]) * nd + b2
__global__ __launch_bounds__(256) void agg2_kernel(const float* __restrict__ h2,
                                                   const int* __restrict__ csr,
                                                   const int* __restrict__ rowptr,
                                                   const int* __restrict__ deg,
                                                   const float* __restrict__ ndst,
                                                   const float* __restrict__ b2,
                                                   float* __restrict__ out) {
    int wid = threadIdx.x >> 6, lane = threadIdx.x & 63;
    int node = blockIdx.x * 4 + wid;
    if (node >= N_NODES) return;
    int rp = rowptr[node], dg = deg[node];
    float acc[NCLS];
#pragma unroll
    for (int c = 0; c < NCLS; c++) acc[c] = 0.f;
    for (int p = rp + lane; p < rp + dg; p += 64) {
        int s = csr[p];
        const float* hp = h2 + (long)s * NCLS;
#pragma unroll
        for (int c = 0; c < NCLS; c++) acc[c] += hp[c];
    }
    float nd = ndst[node];
#pragma unroll
    for (int c = 0; c < NCLS; c++) {
        float v = acc[c];
#pragma unroll
        for (int off = 1; off < 64; off <<= 1) v += __shfl_xor(v, off);
        if (lane == c) out[(long)node * NCLS + c] = v * nd + b2[c];
    }
}

extern "C" void kernel_launch(void* const* d_in, const int* in_sizes, int n_in,
                              void* d_out, int out_size, void* d_ws, size_t ws_size,
                              hipStream_t stream) {
    const float* X  = (const float*)d_in[0];
    const int* src  = (const int*)d_in[1];
    const int* dst  = (const int*)d_in[2];
    const float* W1 = (const float*)d_in[3];
    const float* b1 = (const float*)d_in[4];
    const float* W2 = (const float*)d_in[5];
    const float* b2 = (const float*)d_in[6];
    float* out = (float*)d_out;

    char* ws = (char*)d_ws;
    int* deg_src = (int*)(ws + O_DEG_SRC);
    int* deg_dst = (int*)(ws + O_DEG_DST);
    int* cursor  = (int*)(ws + O_CURSOR);
    int* rowptr  = (int*)(ws + O_ROWPTR);
    float* nsrc  = (float*)(ws + O_NSRC);
    float* ndst  = (float*)(ws + O_NDST);
    int* bsum    = (int*)(ws + O_BSUM);
    int* boff    = (int*)(ws + O_BOFF);
    int* csr     = (int*)(ws + O_CSR);
    float* h     = (float*)(ws + O_H);
    float* h2    = (float*)(ws + O_H2);

    // zero deg_src/deg_dst/cursor in one shot (they're contiguous in [0, O_ROWPTR))
    hipMemsetAsync(ws, 0, O_ROWPTR, stream);

    const int nb = (N_NODES + 255) / 256;  // 196
    deg_kernel<<<N_EDGES / 256, 256, 0, stream>>>(src, dst, deg_src, deg_dst);
    norm_kernel<<<nb, 256, 0, stream>>>(deg_src, deg_dst, nsrc, ndst);
    scan1_kernel<<<nb, 256, 0, stream>>>(deg_dst, rowptr, bsum);
    scan2_kernel<<<1, 256, 0, stream>>>(bsum, boff, nb);
    scan3_kernel<<<nb, 256, 0, stream>>>(rowptr, deg_dst, boff);
    fill_kernel<<<N_EDGES / 256, 256, 0, stream>>>(src, dst, rowptr, cursor, csr);

    gemm1_kernel<<<(N_NODES + BM - 1) / BM, 256, 0, stream>>>(X, W1, nsrc, h);

    agg1_kernel<<<(N_NODES + 3) / 4, 256, 0, stream>>>(h, csr, rowptr, deg_dst, ndst, nsrc,
                                                       b1, W2, h2);
    agg2_kernel<<<(N_NODES + 3) / 4, 256, 0, stream>>>(h2, csr, rowptr, deg_dst, ndst, b2, out);
}

// Round 3
// 584.651 us; speedup vs baseline: 1.4185x; 1.4185x over previous
//
#include <hip/hip_runtime.h>

#define N_NODES 50000
#define N_EDGES 1600000
#define F_IN 1433
#define HID 128
#define NCLS 7

// ---- workspace layout (bytes), all 64-aligned ----
#define O_DEG_SRC 0u          // N ints   (200000)
#define O_DEG_DST 200704u     // N ints
#define O_CURSOR  401408u     // N ints
#define O_ROWPTR  602112u     // N+1 ints
#define O_NSRC    802816u     // N floats
#define O_NDST    1003520u    // N floats
#define O_BSUM    1204224u    // 256 ints
#define O_BOFF    1205248u    // 256 ints
#define O_CSR     1206272u    // E ints (6400000)
#define O_H       7606272u    // N*128 floats (25600000), 16B aligned
#define O_H2      33206272u   // N*7 floats (1400000)
#define O_W1S     34606336u   // 45*2*4*128*8 shorts = 737280 B (bf16 hi/lo, staged layout)

typedef __attribute__((ext_vector_type(8))) short s8v;   // 8 bf16 (4 VGPRs)
typedef __attribute__((ext_vector_type(4))) float f4v;   // 4 f32

// round-to-nearest-even f32 -> bf16 hi, then residual -> bf16 lo
__device__ __forceinline__ void split_bf16(float v, short& hi, short& lo) {
    unsigned u = __builtin_bit_cast(unsigned, v);
    unsigned r = u + 0x7FFFu + ((u >> 16) & 1u);
    unsigned short h = (unsigned short)(r >> 16);
    float hf = __builtin_bit_cast(float, (unsigned)h << 16);
    float lv = v - hf;
    unsigned u2 = __builtin_bit_cast(unsigned, lv);
    unsigned r2 = u2 + 0x7FFFu + ((u2 >> 16) & 1u);
    hi = (short)h;
    lo = (short)(r2 >> 16);
}

__global__ void deg_kernel(const int* __restrict__ src, const int* __restrict__ dst,
                           int* __restrict__ deg_src, int* __restrict__ deg_dst) {
    int e = blockIdx.x * blockDim.x + threadIdx.x;
    if (e < N_EDGES) {
        atomicAdd(&deg_src[src[e]], 1);
        atomicAdd(&deg_dst[dst[e]], 1);
    }
}

__global__ void norm_kernel(const int* __restrict__ deg_src, const int* __restrict__ deg_dst,
                            float* __restrict__ nsrc, float* __restrict__ ndst) {
    int i = blockIdx.x * blockDim.x + threadIdx.x;
    if (i < N_NODES) {
        nsrc[i] = rsqrtf(fmaxf((float)deg_src[i], 1.0f));
        ndst[i] = rsqrtf(fmaxf((float)deg_dst[i], 1.0f));
    }
}

// per-block inclusive scan of deg -> incl, block totals -> bsum
__global__ void scan1_kernel(const int* __restrict__ deg, int* __restrict__ incl,
                             int* __restrict__ bsum) {
    __shared__ int s[256];
    int t = threadIdx.x;
    int i = blockIdx.x * 256 + t;
    int v = (i < N_NODES) ? deg[i] : 0;
    s[t] = v;
    __syncthreads();
    for (int off = 1; off < 256; off <<= 1) {
        int a = (t >= off) ? s[t - off] : 0;
        __syncthreads();
        s[t] += a;
        __syncthreads();
    }
    if (i < N_NODES) incl[i] = s[t];
    if (t == 255) bsum[blockIdx.x] = s[255];
}

__global__ void scan2_kernel(const int* __restrict__ bsum, int* __restrict__ boff, int nb) {
    __shared__ int s[256];
    int t = threadIdx.x;
    int v = (t < nb) ? bsum[t] : 0;
    s[t] = v;
    __syncthreads();
    for (int off = 1; off < 256; off <<= 1) {
        int a = (t >= off) ? s[t - off] : 0;
        __syncthreads();
        s[t] += a;
        __syncthreads();
    }
    if (t < nb) boff[t] = s[t] - v;  // exclusive
}

__global__ void scan3_kernel(int* __restrict__ rowptr, const int* __restrict__ deg,
                             const int* __restrict__ boff) {
    int i = blockIdx.x * 256 + threadIdx.x;
    if (i < N_NODES) rowptr[i] = rowptr[i] - deg[i] + boff[blockIdx.x];
}

__global__ void fill_kernel(const int* __restrict__ src, const int* __restrict__ dst,
                            const int* __restrict__ rowptr, int* __restrict__ cursor,
                            int* __restrict__ csr) {
    int e = blockIdx.x * blockDim.x + threadIdx.x;
    if (e < N_EDGES) {
        int d = dst[e];
        int pos = rowptr[d] + atomicAdd(&cursor[d], 1);
        csr[pos] = src[e];
    }
}

// ---- W1 prep: transpose-free split into the exact LDS staging-granule order ----
// W1S element (s, p, k4, n, j) = split_p( W1[s*32 + k4*8 + j][n] ), zero-padded k>=1433
// flat: W1S[((s*2+p)*4 + k4)*1024 + n*8 + j]
#define KSTEPS 45
__global__ void w1prep_kernel(const float* __restrict__ W1, short* __restrict__ W1S) {
    int t = blockIdx.x * 256 + threadIdx.x;  // (s*4 + k4)*128 + n
    if (t >= KSTEPS * 4 * 128) return;
    int n = t & 127;
    int k4 = (t >> 7) & 3;
    int s = t >> 9;
    long base_hi = ((long)(s * 2 + 0) * 4 + k4) * 1024 + n * 8;
    long base_lo = ((long)(s * 2 + 1) * 4 + k4) * 1024 + n * 8;
#pragma unroll
    for (int j = 0; j < 8; j++) {
        int k = s * 32 + k4 * 8 + j;
        float v = (k < F_IN) ? W1[(long)k * HID + n] : 0.f;
        short hi, lo;
        split_bf16(v, hi, lo);
        W1S[base_hi + j] = hi;
        W1S[base_lo + j] = lo;
    }
}

// ---- GEMM1: h = (X * nsrc[:,None]) @ W1, bf16 hi/lo split MFMA, f32 out ----
// 128x128 tile (BN = HID), BK=32, 4 waves in 2x2, each wave 64x64 = 4x4 frags
#define GBM 128
__global__ __launch_bounds__(256, 2) void gemm1_mfma_kernel(const float* __restrict__ X,
                                                            const short* __restrict__ W1S,
                                                            const float* __restrict__ nsrc,
                                                            float* __restrict__ h) {
    // smem: A region [p][k4][row128][8] at 0 (8192 shorts), B region same at 8192
    __shared__ short smem[16384];
    const int tid = threadIdx.x;
    const int l = tid & 63;
    const int w = tid >> 6;
    const int wm = w >> 1, wn = w & 1;
    const int bm = blockIdx.x * GBM;
    const int k4r = l >> 4;
    const int l15 = l & 15;

    // A staging coords: thread -> (row, 16-wide k chunk)
    const int ar = tid >> 1;
    const int ac = tid & 1;
    const int arow = bm + ar;
    const bool arow_ok = (arow < N_NODES);
    const float ans = arow_ok ? nsrc[arow] : 0.f;
    const float* Xrow = X + (long)(arow_ok ? arow : 0) * F_IN;

    f4v acc[4][4];
#pragma unroll
    for (int i = 0; i < 4; i++)
#pragma unroll
        for (int j = 0; j < 4; j++) acc[i][j] = (f4v){0.f, 0.f, 0.f, 0.f};

    for (int s = 0; s < KSTEPS; ++s) {
        const int k0 = s * 32;
        __syncthreads();
        // ---- stage A: load f32, scale, split hi/lo, ds_write_b128 ----
        {
            const int kbase = k0 + ac * 16;
            const int valid = F_IN - kbase;  // >= 9 always on last step
            float v[16];
            if (arow_ok) {
                if (valid >= 16) {
#pragma unroll
                    for (int j = 0; j < 16; j++) v[j] = Xrow[kbase + j] * ans;
                } else {
#pragma unroll
                    for (int j = 0; j < 16; j++) v[j] = (j < valid) ? Xrow[kbase + j] * ans : 0.f;
                }
            } else {
#pragma unroll
                for (int j = 0; j < 16; j++) v[j] = 0.f;
            }
#pragma unroll
            for (int hh = 0; hh < 2; ++hh) {
                s8v hi8, lo8;
#pragma unroll
                for (int j = 0; j < 8; j++) {
                    short hi, lo;
                    split_bf16(v[hh * 8 + j], hi, lo);
                    hi8[j] = hi;
                    lo8[j] = lo;
                }
                const int k4 = ac * 2 + hh;
                *(s8v*)&smem[((0 + k4) * 128 + ar) * 8] = hi8;
                *(s8v*)&smem[((4 + k4) * 128 + ar) * 8] = lo8;
            }
        }
        // ---- stage B: copy pre-split granules (already in LDS order) ----
        // FULL tile = 2(p) * 4(k4) * 128(n) * 8 = 8192 shorts = 1024 granules
        {
            const short* gsrc = W1S + (long)s * 8192;
#pragma unroll
            for (int i = 0; i < 4; i++) {
                int g = tid + i * 256;
                s8v vv = *(const s8v*)(gsrc + g * 8);
                *(s8v*)&smem[8192 + g * 8] = vv;
            }
        }
        __syncthreads();
        // ---- compute: 16 ds_read_b128 + 48 MFMA ----
        s8v afr[2][4], bfr[2][4];
#pragma unroll
        for (int p = 0; p < 2; p++)
#pragma unroll
            for (int mf = 0; mf < 4; mf++)
                afr[p][mf] = *(const s8v*)&smem[((p * 4 + k4r) * 128 + wm * 64 + mf * 16 + l15) * 8];
#pragma unroll
        for (int p = 0; p < 2; p++)
#pragma unroll
            for (int nf = 0; nf < 4; nf++)
                bfr[p][nf] = *(const s8v*)&smem[8192 + ((p * 4 + k4r) * 128 + wn * 64 + nf * 16 + l15) * 8];
#pragma unroll
        for (int mf = 0; mf < 4; mf++)
#pragma unroll
            for (int nf = 0; nf < 4; nf++) {
                acc[mf][nf] = __builtin_amdgcn_mfma_f32_16x16x32_bf16(afr[0][mf], bfr[0][nf], acc[mf][nf], 0, 0, 0);
                acc[mf][nf] = __builtin_amdgcn_mfma_f32_16x16x32_bf16(afr[0][mf], bfr[1][nf], acc[mf][nf], 0, 0, 0);
                acc[mf][nf] = __builtin_amdgcn_mfma_f32_16x16x32_bf16(afr[1][mf], bfr[0][nf], acc[mf][nf], 0, 0, 0);
            }
    }
    // ---- epilogue: D frag row=(l>>4)*4+reg, col=l&15 ----
#pragma unroll
    for (int mf = 0; mf < 4; mf++) {
        int row0 = bm + wm * 64 + mf * 16 + (l >> 4) * 4;
#pragma unroll
        for (int nf = 0; nf < 4; nf++) {
            int col = wn * 64 + nf * 16 + l15;
#pragma unroll
            for (int r = 0; r < 4; r++) {
                int row = row0 + r;
                if (row < N_NODES) h[(long)row * HID + col] = acc[mf][nf][r];
            }
        }
    }
}

// per dst node: agg = sum h[src], x1' = relu(agg*nd + b1)*ns, h2 = x1' @ W2
__global__ __launch_bounds__(256) void agg1_kernel(const float* __restrict__ h,
                                                   const int* __restrict__ csr,
                                                   const int* __restrict__ rowptr,
                                                   const int* __restrict__ deg,
                                                   const float* __restrict__ ndst,
                                                   const float* __restrict__ nsrc,
                                                   const float* __restrict__ b1,
                                                   const float* __restrict__ W2,
                                                   float* __restrict__ h2) {
    int wid = threadIdx.x >> 6, lane = threadIdx.x & 63;
    int node = blockIdx.x * 4 + wid;
    if (node >= N_NODES) return;
    int rp = rowptr[node], dg = deg[node];
    float acc0 = 0.f, acc1 = 0.f;
    for (int p = rp; p < rp + dg; ++p) {
        int s = csr[p];
        float2 hv = *(const float2*)(h + (long)s * HID + 2 * lane);
        acc0 += hv.x;
        acc1 += hv.y;
    }
    float nd = ndst[node], ns = nsrc[node];
    int k0 = 2 * lane;
    float x0 = fmaxf(acc0 * nd + b1[k0], 0.f) * ns;
    float x1 = fmaxf(acc1 * nd + b1[k0 + 1], 0.f) * ns;
#pragma unroll
    for (int c = 0; c < NCLS; c++) {
        float p = x0 * W2[k0 * NCLS + c] + x1 * W2[(k0 + 1) * NCLS + c];
#pragma unroll
        for (int off = 1; off < 64; off <<= 1) p += __shfl_xor(p, off);
        if (lane == c) h2[(long)node * NCLS + c] = p;
    }
}

// per dst node: out = (sum h2[src]) * nd + b2
__global__ __launch_bounds__(256) void agg2_kernel(const float* __restrict__ h2,
                                                   const int* __restrict__ csr,
                                                   const int* __restrict__ rowptr,
                                                   const int* __restrict__ deg,
                                                   const float* __restrict__ ndst,
                                                   const float* __restrict__ b2,
                                                   float* __restrict__ out) {
    int wid = threadIdx.x >> 6, lane = threadIdx.x & 63;
    int node = blockIdx.x * 4 + wid;
    if (node >= N_NODES) return;
    int rp = rowptr[node], dg = deg[node];
    float acc[NCLS];
#pragma unroll
    for (int c = 0; c < NCLS; c++) acc[c] = 0.f;
    for (int p = rp + lane; p < rp + dg; p += 64) {
        int s = csr[p];
        const float* hp = h2 + (long)s * NCLS;
#pragma unroll
        for (int c = 0; c < NCLS; c++) acc[c] += hp[c];
    }
    float nd = ndst[node];
#pragma unroll
    for (int c = 0; c < NCLS; c++) {
        float v = acc[c];
#pragma unroll
        for (int off = 1; off < 64; off <<= 1) v += __shfl_xor(v, off);
        if (lane == c) out[(long)node * NCLS + c] = v * nd + b2[c];
    }
}

extern "C" void kernel_launch(void* const* d_in, const int* in_sizes, int n_in,
                              void* d_out, int out_size, void* d_ws, size_t ws_size,
                              hipStream_t stream) {
    const float* X  = (const float*)d_in[0];
    const int* src  = (const int*)d_in[1];
    const int* dst  = (const int*)d_in[2];
    const float* W1 = (const float*)d_in[3];
    const float* b1 = (const float*)d_in[4];
    const float* W2 = (const float*)d_in[5];
    const float* b2 = (const float*)d_in[6];
    float* out = (float*)d_out;

    char* ws = (char*)d_ws;
    int* deg_src = (int*)(ws + O_DEG_SRC);
    int* deg_dst = (int*)(ws + O_DEG_DST);
    int* cursor  = (int*)(ws + O_CURSOR);
    int* rowptr  = (int*)(ws + O_ROWPTR);
    float* nsrc  = (float*)(ws + O_NSRC);
    float* ndst  = (float*)(ws + O_NDST);
    int* bsum    = (int*)(ws + O_BSUM);
    int* boff    = (int*)(ws + O_BOFF);
    int* csr     = (int*)(ws + O_CSR);
    float* h     = (float*)(ws + O_H);
    float* h2    = (float*)(ws + O_H2);
    short* W1S   = (short*)(ws + O_W1S);

    hipMemsetAsync(ws, 0, O_ROWPTR, stream);

    const int nb = (N_NODES + 255) / 256;  // 196
    w1prep_kernel<<<(KSTEPS * 4 * 128 + 255) / 256, 256, 0, stream>>>(W1, W1S);
    deg_kernel<<<N_EDGES / 256, 256, 0, stream>>>(src, dst, deg_src, deg_dst);
    norm_kernel<<<nb, 256, 0, stream>>>(deg_src, deg_dst, nsrc, ndst);
    scan1_kernel<<<nb, 256, 0, stream>>>(deg_dst, rowptr, bsum);
    scan2_kernel<<<1, 256, 0, stream>>>(bsum, boff, nb);
    scan3_kernel<<<nb, 256, 0, stream>>>(rowptr, deg_dst, boff);
    fill_kernel<<<N_EDGES / 256, 256, 0, stream>>>(src, dst, rowptr, cursor, csr);

    gemm1_mfma_kernel<<<(N_NODES + GBM - 1) / GBM, 256, 0, stream>>>(X, W1S, nsrc, h);

    agg1_kernel<<<(N_NODES + 3) / 4, 256, 0, stream>>>(h, csr, rowptr, deg_dst, ndst, nsrc,
                                                       b1, W2, h2);
    agg2_kernel<<<(N_NODES + 3) / 4, 256, 0, stream>>>(h2, csr, rowptr, deg_dst, ndst, b2, out);
}

// Round 4
// 507.431 us; speedup vs baseline: 1.6344x; 1.1522x over previous
//
#include <hip/hip_runtime.h>

#define N_NODES 50000
#define N_EDGES 1600000
#define F_IN 1433
#define HID 128
#define NCLS 7
#define KSTEPS 45

// ---- workspace layout (bytes), all 256-aligned ----
#define O_DEG_SRC 0u          // N ints   (200000)
#define O_DEG_DST 200704u     // N ints
#define O_CURSOR  401408u     // N ints
#define O_ROWPTR  602112u     // N+1 ints
#define O_NSRC    802816u     // N floats
#define O_NDST    1003520u    // N floats
#define O_BSUM    1204224u    // 256 ints
#define O_BOFF    1205248u    // 256 ints
#define O_CSR     1206272u    // E ints (6400000)
#define O_H       7606272u    // N*128 floats (25600000), 16B aligned
#define O_H2      33206272u   // N*8 floats padded (1600000)
#define O_W1S     34806272u   // 45*2*4*128*8 shorts = 737280 B (bf16 hi/lo, staged layout)

typedef __attribute__((ext_vector_type(8))) short s8v;   // 8 bf16 (4 VGPRs)
typedef __attribute__((ext_vector_type(4))) float f4v;   // 4 f32

// round-to-nearest-even f32 -> bf16 hi, then residual -> bf16 lo
__device__ __forceinline__ void split_bf16(float v, short& hi, short& lo) {
    unsigned u = __builtin_bit_cast(unsigned, v);
    unsigned r = u + 0x7FFFu + ((u >> 16) & 1u);
    unsigned short h = (unsigned short)(r >> 16);
    float hf = __builtin_bit_cast(float, (unsigned)h << 16);
    float lv = v - hf;
    unsigned u2 = __builtin_bit_cast(unsigned, lv);
    unsigned r2 = u2 + 0x7FFFu + ((u2 >> 16) & 1u);
    hi = (short)h;
    lo = (short)(r2 >> 16);
}

// async global->LDS, 16B per lane; lds ptr must be wave-uniform (CK-style casts)
__device__ __forceinline__ void gload_lds16(const void* g, void* l) {
    const __attribute__((address_space(1))) unsigned int* gp =
        (const __attribute__((address_space(1))) unsigned int*)(unsigned long long)g;
    __attribute__((address_space(3))) unsigned int* lp =
        (__attribute__((address_space(3))) unsigned int*)(unsigned long long)(l);
    __builtin_amdgcn_global_load_lds(gp, lp, 16, 0, 0);
}

__global__ void deg_kernel(const int* __restrict__ src, const int* __restrict__ dst,
                           int* __restrict__ deg_src, int* __restrict__ deg_dst) {
    int e = blockIdx.x * blockDim.x + threadIdx.x;
    if (e < N_EDGES) {
        atomicAdd(&deg_src[src[e]], 1);
        atomicAdd(&deg_dst[dst[e]], 1);
    }
}

__global__ void norm_kernel(const int* __restrict__ deg_src, const int* __restrict__ deg_dst,
                            float* __restrict__ nsrc, float* __restrict__ ndst) {
    int i = blockIdx.x * blockDim.x + threadIdx.x;
    if (i < N_NODES) {
        nsrc[i] = rsqrtf(fmaxf((float)deg_src[i], 1.0f));
        ndst[i] = rsqrtf(fmaxf((float)deg_dst[i], 1.0f));
    }
}

// per-block inclusive scan of deg -> incl, block totals -> bsum
__global__ void scan1_kernel(const int* __restrict__ deg, int* __restrict__ incl,
                             int* __restrict__ bsum) {
    __shared__ int s[256];
    int t = threadIdx.x;
    int i = blockIdx.x * 256 + t;
    int v = (i < N_NODES) ? deg[i] : 0;
    s[t] = v;
    __syncthreads();
    for (int off = 1; off < 256; off <<= 1) {
        int a = (t >= off) ? s[t - off] : 0;
        __syncthreads();
        s[t] += a;
        __syncthreads();
    }
    if (i < N_NODES) incl[i] = s[t];
    if (t == 255) bsum[blockIdx.x] = s[255];
}

__global__ void scan2_kernel(const int* __restrict__ bsum, int* __restrict__ boff, int nb) {
    __shared__ int s[256];
    int t = threadIdx.x;
    int v = (t < nb) ? bsum[t] : 0;
    s[t] = v;
    __syncthreads();
    for (int off = 1; off < 256; off <<= 1) {
        int a = (t >= off) ? s[t - off] : 0;
        __syncthreads();
        s[t] += a;
        __syncthreads();
    }
    if (t < nb) boff[t] = s[t] - v;  // exclusive
}

__global__ void scan3_kernel(int* __restrict__ rowptr, const int* __restrict__ deg,
                             const int* __restrict__ boff) {
    int i = blockIdx.x * 256 + threadIdx.x;
    if (i < N_NODES) rowptr[i] = rowptr[i] - deg[i] + boff[blockIdx.x];
}

__global__ void fill_kernel(const int* __restrict__ src, const int* __restrict__ dst,
                            const int* __restrict__ rowptr, int* __restrict__ cursor,
                            int* __restrict__ csr) {
    int e = blockIdx.x * blockDim.x + threadIdx.x;
    if (e < N_EDGES) {
        int d = dst[e];
        int pos = rowptr[d] + atomicAdd(&cursor[d], 1);
        csr[pos] = src[e];
    }
}

// ---- W1 prep: split into the exact LDS staging-granule order ----
// granule g within step s: (p*4 + k4)*128 + n ; element j: W1[s*32 + k4*8 + j][n]
__global__ void w1prep_kernel(const float* __restrict__ W1, short* __restrict__ W1S) {
    int t = blockIdx.x * 256 + threadIdx.x;  // (s*4 + k4)*128 + n
    if (t >= KSTEPS * 4 * 128) return;
    int n = t & 127;
    int k4 = (t >> 7) & 3;
    int s = t >> 9;
    long base_hi = (long)s * 8192 + ((0 * 4 + k4) * 128 + n) * 8;
    long base_lo = (long)s * 8192 + ((1 * 4 + k4) * 128 + n) * 8;
#pragma unroll
    for (int j = 0; j < 8; j++) {
        int k = s * 32 + k4 * 8 + j;
        float v = (k < F_IN) ? W1[(long)k * HID + n] : 0.f;
        short hi, lo;
        split_bf16(v, hi, lo);
        W1S[base_hi + j] = hi;
        W1S[base_lo + j] = lo;
    }
}

// ---- GEMM1: h = (X * nsrc[:,None]) @ W1, bf16 hi/lo split MFMA, f32 out ----
// 64x128 tile, BK=32, 4 waves in 2x2 (wave tile 32x64), A double-buffered (reg-prefetch),
// B single-buffered via global_load_lds (W1S is L2-hot).
#define GBM 64
__global__ __launch_bounds__(256, 3) void gemm1_mfma_kernel(const float* __restrict__ X,
                                                            const short* __restrict__ W1S,
                                                            const float* __restrict__ nsrc,
                                                            float* __restrict__ h) {
    // shorts: A0 @0 (4096), A1 @4096 (4096), B @8192 (8192). total 32 KB.
    __shared__ __align__(16) short smem[16384];
    const int tid = threadIdx.x;
    const int l = tid & 63;
    const int w = tid >> 6;
    const int wm = w >> 1, wn = w & 1;
    const int k4r = l >> 4;
    const int l15 = l & 15;
    const int bm = blockIdx.x * GBM;

    // A staging: thread -> (row ar, 8-wide k chunk ac)
    const int ar = tid >> 2, ac = tid & 3;
    const int arow = bm + ar;
    const bool ok = (arow < N_NODES);
    const float ans = ok ? nsrc[arow] : 0.f;
    const float* Xrow = X + (long)(ok ? arow : 0) * F_IN + ac * 8;

    f4v acc[2][4];
#pragma unroll
    for (int i = 0; i < 2; i++)
#pragma unroll
        for (int j = 0; j < 4; j++) acc[i][j] = (f4v){0.f, 0.f, 0.f, 0.f};

    float xv[8];

#define LOAD_X(S)                                                                  \
    do {                                                                           \
        if ((S) != KSTEPS - 1) {                                                   \
            if (ok) {                                                              \
                float4 _a = *(const float4*)(Xrow + (S) * 32);                     \
                float4 _b = *(const float4*)(Xrow + (S) * 32 + 4);                 \
                xv[0] = _a.x; xv[1] = _a.y; xv[2] = _a.z; xv[3] = _a.w;            \
                xv[4] = _b.x; xv[5] = _b.y; xv[6] = _b.z; xv[7] = _b.w;            \
            } else {                                                               \
                for (int _j = 0; _j < 8; _j++) xv[_j] = 0.f;                       \
            }                                                                      \
        } else {                                                                   \
            for (int _j = 0; _j < 8; _j++) {                                       \
                int _k = (S) * 32 + ac * 8 + _j;                                   \
                xv[_j] = (ok && _k < F_IN) ? Xrow[(S) * 32 + _j] : 0.f;            \
            }                                                                      \
        }                                                                          \
    } while (0)

#define SPLIT_WRITE(ABUF)                                                          \
    do {                                                                           \
        s8v _hi8, _lo8;                                                            \
        for (int _j = 0; _j < 8; _j++) {                                           \
            short _hi, _lo;                                                        \
            split_bf16(xv[_j] * ans, _hi, _lo);                                    \
            _hi8[_j] = _hi; _lo8[_j] = _lo;                                        \
        }                                                                          \
        int _base = (ABUF) * 4096;                                                 \
        *(s8v*)&smem[_base + ((0 + ac) * 64 + ar) * 8] = _hi8;                     \
        *(s8v*)&smem[_base + ((4 + ac) * 64 + ar) * 8] = _lo8;                     \
    } while (0)

#define STAGE_B(S)                                                                 \
    do {                                                                           \
        const short* _gb = W1S + (long)(S) * 8192;                                 \
        _Pragma("unroll") for (int _i = 0; _i < 4; _i++) {                         \
            int _g0 = (_i * 4 + w) * 64;                                           \
            gload_lds16(_gb + (_g0 + l) * 8, &smem[8192 + _g0 * 8]);               \
        }                                                                          \
    } while (0)

    // prologue: stage step 0
    LOAD_X(0);
    STAGE_B(0);
    SPLIT_WRITE(0);
    __syncthreads();

    int cur = 0;
    for (int s = 0; s < KSTEPS; ++s) {
        if (s + 1 < KSTEPS) LOAD_X(s + 1);  // global loads in flight over MFMA phase
        {
            const int abase = cur * 4096;
            s8v afr[2][2], bfr[2][4];
#pragma unroll
            for (int p = 0; p < 2; p++)
#pragma unroll
                for (int mf = 0; mf < 2; mf++)
                    afr[p][mf] = *(const s8v*)&smem[abase + ((p * 4 + k4r) * 64 + wm * 32 + mf * 16 + l15) * 8];
#pragma unroll
            for (int p = 0; p < 2; p++)
#pragma unroll
                for (int nf = 0; nf < 4; nf++)
                    bfr[p][nf] = *(const s8v*)&smem[8192 + ((p * 4 + k4r) * 128 + wn * 64 + nf * 16 + l15) * 8];
#pragma unroll
            for (int mf = 0; mf < 2; mf++)
#pragma unroll
                for (int nf = 0; nf < 4; nf++) {
                    acc[mf][nf] = __builtin_amdgcn_mfma_f32_16x16x32_bf16(afr[0][mf], bfr[0][nf], acc[mf][nf], 0, 0, 0);
                    acc[mf][nf] = __builtin_amdgcn_mfma_f32_16x16x32_bf16(afr[0][mf], bfr[1][nf], acc[mf][nf], 0, 0, 0);
                    acc[mf][nf] = __builtin_amdgcn_mfma_f32_16x16x32_bf16(afr[1][mf], bfr[0][nf], acc[mf][nf], 0, 0, 0);
                }
        }
        __syncthreads();  // B reads done by all waves
        if (s + 1 < KSTEPS) {
            STAGE_B(s + 1);        // async DMA into B
            SPLIT_WRITE(cur ^ 1);  // A into the other buffer (xv has s+1)
            __syncthreads();       // stages visible (drains DMA)
            cur ^= 1;
        }
    }

    // epilogue: D frag row=(l>>4)*4+reg, col=l&15
#pragma unroll
    for (int mf = 0; mf < 2; mf++) {
        int row0 = bm + wm * 32 + mf * 16 + (l >> 4) * 4;
#pragma unroll
        for (int nf = 0; nf < 4; nf++) {
            int col = wn * 64 + nf * 16 + l15;
#pragma unroll
            for (int r = 0; r < 4; r++) {
                int row = row0 + r;
                if (row < N_NODES) h[(long)row * HID + col] = acc[mf][nf][r];
            }
        }
    }
#undef LOAD_X
#undef SPLIT_WRITE
#undef STAGE_B
}

// per dst node: agg = sum h[src], x1' = relu(agg*nd + b1)*ns, h2 = x1' @ W2 (stride-8 padded)
__global__ __launch_bounds__(256) void agg1_kernel(const float* __restrict__ h,
                                                   const int* __restrict__ csr,
                                                   const int* __restrict__ rowptr,
                                                   const int* __restrict__ deg,
                                                   const float* __restrict__ ndst,
                                                   const float* __restrict__ nsrc,
                                                   const float* __restrict__ b1,
                                                   const float* __restrict__ W2,
                                                   float* __restrict__ h2p) {
    int wid = threadIdx.x >> 6, lane = threadIdx.x & 63;
    int node = blockIdx.x * 4 + wid;
    if (node >= N_NODES) return;
    int p = rowptr[node];
    int end = p + deg[node];
    float acc0 = 0.f, acc1 = 0.f;
    const float* hb = h + 2 * lane;
    // 8-deep MLP: 8 independent 512B row-gathers in flight
    for (; p + 8 <= end; p += 8) {
        int s0 = csr[p + 0], s1 = csr[p + 1], s2 = csr[p + 2], s3 = csr[p + 3];
        int s4 = csr[p + 4], s5 = csr[p + 5], s6 = csr[p + 6], s7 = csr[p + 7];
        float2 v0 = *(const float2*)(hb + (long)s0 * HID);
        float2 v1 = *(const float2*)(hb + (long)s1 * HID);
        float2 v2 = *(const float2*)(hb + (long)s2 * HID);
        float2 v3 = *(const float2*)(hb + (long)s3 * HID);
        float2 v4 = *(const float2*)(hb + (long)s4 * HID);
        float2 v5 = *(const float2*)(hb + (long)s5 * HID);
        float2 v6 = *(const float2*)(hb + (long)s6 * HID);
        float2 v7 = *(const float2*)(hb + (long)s7 * HID);
        acc0 += ((v0.x + v1.x) + (v2.x + v3.x)) + ((v4.x + v5.x) + (v6.x + v7.x));
        acc1 += ((v0.y + v1.y) + (v2.y + v3.y)) + ((v4.y + v5.y) + (v6.y + v7.y));
    }
    for (; p < end; ++p) {
        int s = csr[p];
        float2 v = *(const float2*)(hb + (long)s * HID);
        acc0 += v.x;
        acc1 += v.y;
    }
    float nd = ndst[node], ns = nsrc[node];
    int k0 = 2 * lane;
    float x0 = fmaxf(acc0 * nd + b1[k0], 0.f) * ns;
    float x1 = fmaxf(acc1 * nd + b1[k0 + 1], 0.f) * ns;
#pragma unroll
    for (int c = 0; c < NCLS; c++) {
        float q = x0 * W2[k0 * NCLS + c] + x1 * W2[(k0 + 1) * NCLS + c];
#pragma unroll
        for (int off = 1; off < 64; off <<= 1) q += __shfl_xor(q, off);
        if (lane == c) h2p[(long)node * 8 + c] = q;
    }
    if (lane == 7) h2p[(long)node * 8 + 7] = 0.f;
}

// per dst node: out = (sum h2[src]) * nd + b2  (h2 stride-8, 2x float4 per edge)
__global__ __launch_bounds__(256) void agg2_kernel(const float* __restrict__ h2p,
                                                   const int* __restrict__ csr,
                                                   const int* __restrict__ rowptr,
                                                   const int* __restrict__ deg,
                                                   const float* __restrict__ ndst,
                                                   const float* __restrict__ b2,
                                                   float* __restrict__ out) {
    int wid = threadIdx.x >> 6, lane = threadIdx.x & 63;
    int node = blockIdx.x * 4 + wid;
    if (node >= N_NODES) return;
    int rp = rowptr[node], end = rp + deg[node];
    float a0 = 0.f, a1 = 0.f, a2 = 0.f, a3 = 0.f, a4 = 0.f, a5 = 0.f, a6 = 0.f;
    for (int p = rp + lane; p < end; p += 64) {
        int s = csr[p];
        const float4* r = (const float4*)(h2p + (long)s * 8);
        float4 lo = r[0], hi = r[1];
        a0 += lo.x; a1 += lo.y; a2 += lo.z; a3 += lo.w;
        a4 += hi.x; a5 += hi.y; a6 += hi.z;
    }
    float nd = ndst[node];
    float acc[NCLS] = {a0, a1, a2, a3, a4, a5, a6};
#pragma unroll
    for (int c = 0; c < NCLS; c++) {
        float v = acc[c];
#pragma unroll
        for (int off = 1; off < 64; off <<= 1) v += __shfl_xor(v, off);
        if (lane == c) out[(long)node * NCLS + c] = v * nd + b2[c];
    }
}

extern "C" void kernel_launch(void* const* d_in, const int* in_sizes, int n_in,
                              void* d_out, int out_size, void* d_ws, size_t ws_size,
                              hipStream_t stream) {
    const float* X  = (const float*)d_in[0];
    const int* src  = (const int*)d_in[1];
    const int* dst  = (const int*)d_in[2];
    const float* W1 = (const float*)d_in[3];
    const float* b1 = (const float*)d_in[4];
    const float* W2 = (const float*)d_in[5];
    const float* b2 = (const float*)d_in[6];
    float* out = (float*)d_out;

    char* ws = (char*)d_ws;
    int* deg_src = (int*)(ws + O_DEG_SRC);
    int* deg_dst = (int*)(ws + O_DEG_DST);
    int* cursor  = (int*)(ws + O_CURSOR);
    int* rowptr  = (int*)(ws + O_ROWPTR);
    float* nsrc  = (float*)(ws + O_NSRC);
    float* ndst  = (float*)(ws + O_NDST);
    int* bsum    = (int*)(ws + O_BSUM);
    int* boff    = (int*)(ws + O_BOFF);
    int* csr     = (int*)(ws + O_CSR);
    float* h     = (float*)(ws + O_H);
    float* h2p   = (float*)(ws + O_H2);
    short* W1S   = (short*)(ws + O_W1S);

    hipMemsetAsync(ws, 0, O_ROWPTR, stream);

    const int nb = (N_NODES + 255) / 256;  // 196
    w1prep_kernel<<<(KSTEPS * 4 * 128 + 255) / 256, 256, 0, stream>>>(W1, W1S);
    deg_kernel<<<N_EDGES / 256, 256, 0, stream>>>(src, dst, deg_src, deg_dst);
    norm_kernel<<<nb, 256, 0, stream>>>(deg_src, deg_dst, nsrc, ndst);
    scan1_kernel<<<nb, 256, 0, stream>>>(deg_dst, rowptr, bsum);
    scan2_kernel<<<1, 256, 0, stream>>>(bsum, boff, nb);
    scan3_kernel<<<nb, 256, 0, stream>>>(rowptr, deg_dst, boff);
    fill_kernel<<<N_EDGES / 256, 256, 0, stream>>>(src, dst, rowptr, cursor, csr);

    gemm1_mfma_kernel<<<(N_NODES + GBM - 1) / GBM, 256, 0, stream>>>(X, W1S, nsrc, h);

    agg1_kernel<<<(N_NODES + 3) / 4, 256, 0, stream>>>(h, csr, rowptr, deg_dst, ndst, nsrc,
                                                       b1, W2, h2p);
    agg2_kernel<<<(N_NODES + 3) / 4, 256, 0, stream>>>(h2p, csr, rowptr, deg_dst, ndst, b2, out);
}